// Round 9
// baseline (38502.951 us; speedup 1.0000x reference)
//
#include <hip/hip_runtime.h>
#include <hip/hip_bf16.h>
#include <stdint.h>

// Neural ODE (RK4, 32 steps) over a 5-layer MLP, B=32768, VAR_DIM=50 (pad 64).
// bf16 MFMA GEMMs (16x16x32), fp32 accum, fp32 state y.
// concat(h,t) @ W == h @ W[:K] + (b + t*W[K]) -> time column folded into bias.
// r8: gemm256 = 4 waves x (128x128 per-wave tile). DS-pipe accounting showed
//     the 8-wave version was LDS-read-bound (192 reads/CU/tile = 2304 cyc vs
//     621 MFMA); 4 waves with fatter per-wave tiles cut reads to 128/CU/tile.
//     512-VGPR budget at 1 wave/SIMD holds acc(256) + frags(128).

typedef __bf16 bf16_t;
typedef bf16_t bf16x8 __attribute__((ext_vector_type(8)));
typedef float  f32x4  __attribute__((ext_vector_type(4)));

#define DEVI static __device__ __forceinline__

DEVI void gload_lds16(const bf16_t* gsrc, bf16_t* ldst) {
  __builtin_amdgcn_global_load_lds(
      (const __attribute__((address_space(1))) uint32_t*)gsrc,
      (__attribute__((address_space(3))) uint32_t*)ldst,
      16, 0, 0);
}

// ---------------------------------------------------------------------------
// 256x256 tile, BK=64, 4 waves (2Mx2N, 128x128 each), double-buffered LDS.
// LDS swizzle: physical_col_byte = logical ^ bit5*(row&4) ^ bit6*(row&8),
// staged via linear global_load_lds dest + pre-swizzled global SOURCE col.
// Schedule per K-tile (r7 pipelining, adapted):
//   stage T+1 (16 gloads) ; read kk1 frags (16) ; MFMA kk0 (64)
//   lgkm0+vmcnt0+barrier ; read next-tile kk0 frags (16) ; MFMA kk1 (64)
// ---------------------------------------------------------------------------
template<int K>
__global__ __launch_bounds__(256, 1) void gemm256(
    const bf16_t* __restrict__ A,     // M x K row-major
    const bf16_t* __restrict__ BT,    // N x K row-major (pre-transposed W)
    const float* __restrict__ bias,
    const float* __restrict__ wtime,
    float t,
    bf16_t* __restrict__ C, int ldc,
    int M, int N)
{
  constexpr int NT = K / 64;          // K-tiles
  static_assert(NT >= 2, "need >=2 K-tiles");

  __shared__ __align__(16) bf16_t As[2][256][64];
  __shared__ __align__(16) bf16_t Bs[2][256][64];

  const int tid  = threadIdx.x;
  const int wave = tid >> 6;          // 0..3
  const int lane = tid & 63;
  const int wr = wave >> 1;           // 0..1 -> 128-row half
  const int wc = wave & 1;            // 0..1 -> 128-col half

  // T1: XCD-aware bijective swizzle (gridDim.x % 8 == 0 by construction)
  int wg = blockIdx.x;
  {
    const int cpx = gridDim.x >> 3;
    wg = (wg & 7) * cpx + (wg >> 3);
  }
  const int nbn = N >> 8;
  const int bm = (wg / nbn) << 8;
  const int bn = (wg % nbn) << 8;

  // staging: slab i covers rows i*32 + wave*8 + (lane>>3); 16B per lane.
  //   dest row bits: r&4 = lane&32-bit, r&8 = wave&1 -> pre-swizzled src col.
  const int srow = lane >> 3;
  const int scol = ((lane & 7) << 3) ^ ((lane & 32) >> 1) ^ ((wave & 1) << 5);
  const bf16_t* aS = A  + (size_t)(bm + wave * 8 + srow) * K + scol;
  const bf16_t* bS = BT + (size_t)(bn + wave * 8 + srow) * K + scol;
  bf16_t* aD = &As[0][0][0] + wave * 8 * 64;   // wave-uniform LDS base
  bf16_t* bD = &Bs[0][0][0] + wave * 8 * 64;

  auto stageTile = [&](int kt) {
    const int buf = kt & 1;
#pragma unroll
    for (int i = 0; i < 8; ++i) {
      gload_lds16(aS + (size_t)(i * 32) * K + kt * 64, aD + (buf * 256 + i * 32) * 64);
      gload_lds16(bS + (size_t)(i * 32) * K + kt * 64, bD + (buf * 256 + i * 32) * 64);
    }
  };

  const int fr = lane & 15;
  const int fq = lane >> 4;
  const int rsw = ((fr & 4) << 3) ^ ((fr & 8) << 3);   // byte-XOR from row bits

  bf16x8 a0[8], a1[8];     // A frags for kk=0 / kk=1  [m]
  bf16x8 b0[8], b1[8];     // B frags for kk=0 / kk=1  [n]
  f32x4  acc[8][8] = {};   // 128x128 per-wave output

  auto lda_kk = [&](bf16x8 (&dst)[8], int buf, int kk) {
    const char* base = (const char*)&As[buf][0][0];
#pragma unroll
    for (int m = 0; m < 8; ++m) {
      int r  = wr * 128 + m * 16 + fr;
      int cb = (kk * 64 + fq * 16) ^ rsw;
      dst[m] = *(const bf16x8*)(base + r * 128 + cb);
    }
  };
  auto ldb_kk = [&](bf16x8 (&dst)[8], int buf, int kk) {
    const char* base = (const char*)&Bs[buf][0][0];
#pragma unroll
    for (int n = 0; n < 8; ++n) {
      int r  = wc * 128 + n * 16 + fr;
      int cb = (kk * 64 + fq * 16) ^ rsw;
      dst[n] = *(const bf16x8*)(base + r * 128 + cb);
    }
  };
  auto mma_all = [&](bf16x8 (&a)[8], bf16x8 (&b)[8]) {
    __builtin_amdgcn_s_setprio(1);
#pragma unroll
    for (int m = 0; m < 8; ++m)
#pragma unroll
      for (int n = 0; n < 8; ++n)
        acc[m][n] = __builtin_amdgcn_mfma_f32_16x16x32_bf16(
            a[m], b[n], acc[m][n], 0, 0, 0);
    __builtin_amdgcn_s_setprio(0);
  };

  // prologue
  stageTile(0);
  asm volatile("s_waitcnt vmcnt(0)" ::: "memory");
  __builtin_amdgcn_s_barrier();
  lda_kk(a0, 0, 0);
  ldb_kk(b0, 0, 0);

  for (int t2 = 0; t2 < NT; ++t2) {
    const int buf = t2 & 1;
    if (t2 + 1 < NT) stageTile(t2 + 1);   // 16 gloads -> other buffer
    lda_kk(a1, buf, 1);                   // 16 reads (this tile, kk=1)
    ldb_kk(b1, buf, 1);
    mma_all(a0, b0);                      // 64 MFMA (kk=0)
    if (t2 + 1 < NT) {
      asm volatile("s_waitcnt lgkmcnt(0)" ::: "memory");  // buf-reads drained (cheap: ~300cyc old)
      asm volatile("s_waitcnt vmcnt(0)" ::: "memory");    // T+1 staged (ours)
      __builtin_amdgcn_s_barrier();                       // all waves staged + drained
      lda_kk(a0, buf ^ 1, 0);             // next-tile kk=0 reads overlap kk=1 MFMAs
      ldb_kk(b0, buf ^ 1, 0);
    }
    mma_all(a1, b1);                      // 64 MFMA (kk=1)
  }

  // epilogue: bias(t) + ReLU, bf16 out
#pragma unroll
  for (int n = 0; n < 8; ++n) {
    const int gcol = bn + wc * 128 + n * 16 + fr;
    const float bv = bias[gcol] + t * wtime[gcol];
#pragma unroll
    for (int m = 0; m < 8; ++m) {
      const int grow0 = bm + wr * 128 + m * 16 + (fq << 2);
#pragma unroll
      for (int r = 0; r < 4; ++r) {
        float v = acc[m][n][r] + bv;
        v = v > 0.0f ? v : 0.0f;
        C[(size_t)(grow0 + r) * ldc + gcol] = (bf16_t)v;
      }
    }
  }
}

// ---------------------------------------------------------------------------
// 128^2 kernel for layer 0 (K=64), full bank-spread swizzle.
// ---------------------------------------------------------------------------
template<int BM, int BN, int BK, int WROWS, int WCOLS, bool RELU, bool OUT_BF16>
__global__ __launch_bounds__(256) void gemm_bt(
    const bf16_t* __restrict__ A, int lda,
    const bf16_t* __restrict__ BT,
    const float* __restrict__ bias,
    const float* __restrict__ wtime,
    float t,
    void* __restrict__ Cv, int ldc,
    int M, int K)
{
  static_assert(BK == 64, "swizzle assumes BK=64");
  constexpr int MR  = BM / WROWS / 16;
  constexpr int NR  = BN / WCOLS / 16;
  constexpr int TPR = BK / 8;        // 8
  constexpr int RPW = 64 / TPR;      // 8
  constexpr int RPL = 4 * RPW;       // 32
  static_assert(BM % RPL == 0 && BN % RPL == 0, "tile staging mismatch");

  __shared__ bf16_t As[BM][BK];
  __shared__ bf16_t Bs[BN][BK];

  const int tid  = threadIdx.x;
  const int wave = tid >> 6;
  const int lane = tid & 63;
  const int wr = wave / WCOLS;
  const int wc = wave % WCOLS;
  const int bm = blockIdx.x * BM;
  const int bn = blockIdx.y * BN;
  const int lrow = lane >> 3;
  const int lcol = (((lane & 7) << 3) ^ ((lane & 32) >> 1) ^ ((wave & 1) << 5));

  const int fr = lane & 15;
  const int fq = lane >> 4;
  const int esw = ((fr & 4) << 2) ^ ((fr & 8) << 2);  // element-XOR from row bits

  f32x4 acc[MR][NR] = {};

  for (int k0 = 0; k0 < K; k0 += BK) {
#pragma unroll
    for (int i = 0; i < BM / RPL; ++i) {
      const int rb = i * RPL + wave * RPW;
      gload_lds16(&A[(size_t)(bm + rb + lrow) * lda + k0 + lcol], &As[rb][0]);
    }
#pragma unroll
    for (int i = 0; i < BN / RPL; ++i) {
      const int rb = i * RPL + wave * RPW;
      gload_lds16(&BT[(size_t)(bn + rb + lrow) * K + k0 + lcol], &Bs[rb][0]);
    }
    __syncthreads();
#pragma unroll
    for (int kk = 0; kk < BK / 32; ++kk) {
      bf16x8 af[MR], bfr[NR];
      const int ecol = (kk * 32 + fq * 8) ^ esw;
#pragma unroll
      for (int m = 0; m < MR; ++m)
        af[m] = *(const bf16x8*)&As[wr * (BM / WROWS) + m * 16 + fr][ecol];
#pragma unroll
      for (int n = 0; n < NR; ++n)
        bfr[n] = *(const bf16x8*)&Bs[wc * (BN / WCOLS) + n * 16 + fr][ecol];
#pragma unroll
      for (int m = 0; m < MR; ++m)
#pragma unroll
        for (int n = 0; n < NR; ++n)
          acc[m][n] = __builtin_amdgcn_mfma_f32_16x16x32_bf16(
              af[m], bfr[n], acc[m][n], 0, 0, 0);
    }
    __syncthreads();
  }

#pragma unroll
  for (int n = 0; n < NR; ++n) {
    const int gcol = bn + wc * (BN / WCOLS) + n * 16 + fr;
    const float bv = bias[gcol] + t * wtime[gcol];
#pragma unroll
    for (int m = 0; m < MR; ++m) {
      const int grow0 = bm + wr * (BM / WROWS) + m * 16 + (fq << 2);
#pragma unroll
      for (int r = 0; r < 4; ++r) {
        float v = acc[m][n][r] + bv;
        if (RELU) v = v > 0.0f ? v : 0.0f;
        if constexpr (OUT_BF16)
          ((bf16_t*)Cv)[(size_t)(grow0 + r) * ldc + gcol] = (bf16_t)v;
        else
          ((float*)Cv)[(size_t)(grow0 + r) * ldc + gcol] = v;
      }
    }
  }
}

// ---------------------------------------------------------------------------
// Layer 4 (N=64, K=1024) with RK4 combine fused into the epilogue.
// BM=64, BN=64, 4 waves (2x2) -> 512 blocks = 2 blocks/CU.  Swizzled LDS.
// ---------------------------------------------------------------------------
__global__ __launch_bounds__(256) void gemm_l4_rk4(
    const bf16_t* __restrict__ A, int lda,
    const bf16_t* __restrict__ BT,
    const float* __restrict__ bias,
    const float* __restrict__ wtime,
    float t,
    float* __restrict__ y, float* __restrict__ accb,
    bf16_t* __restrict__ ybf,
    float ca, float cs, int mode,
    int M, int K)
{
  constexpr int BM = 64, BN = 64, BK = 64;
  constexpr int MR = 2, NR = 2;

  __shared__ bf16_t As[BM][BK];
  __shared__ bf16_t Bs[BN][BK];

  const int tid  = threadIdx.x;
  const int wave = tid >> 6;
  const int lane = tid & 63;
  const int wr = wave >> 1;
  const int wc = wave & 1;
  const int bm = blockIdx.x * BM;
  const int lrow = lane >> 3;
  const int lcol = (((lane & 7) << 3) ^ ((lane & 32) >> 1) ^ ((wave & 1) << 5));

  const int fr = lane & 15;
  const int fq = lane >> 4;
  const int esw = ((fr & 4) << 2) ^ ((fr & 8) << 2);

  f32x4 acc[MR][NR] = {};

  for (int k0 = 0; k0 < K; k0 += BK) {
#pragma unroll
    for (int i = 0; i < 2; ++i) {
      const int rb = i * 32 + wave * 8;
      gload_lds16(&A[(size_t)(bm + rb + lrow) * lda + k0 + lcol], &As[rb][0]);
    }
#pragma unroll
    for (int i = 0; i < 2; ++i) {
      const int rb = i * 32 + wave * 8;
      gload_lds16(&BT[(size_t)(rb + lrow) * K + k0 + lcol], &Bs[rb][0]);
    }
    __syncthreads();
#pragma unroll
    for (int kk = 0; kk < 2; ++kk) {
      bf16x8 af[MR], bfr[NR];
      const int ecol = (kk * 32 + fq * 8) ^ esw;
#pragma unroll
      for (int m = 0; m < MR; ++m)
        af[m] = *(const bf16x8*)&As[wr * 32 + m * 16 + fr][ecol];
#pragma unroll
      for (int n = 0; n < NR; ++n)
        bfr[n] = *(const bf16x8*)&Bs[wc * 32 + n * 16 + fr][ecol];
#pragma unroll
      for (int m = 0; m < MR; ++m)
#pragma unroll
        for (int n = 0; n < NR; ++n)
          acc[m][n] = __builtin_amdgcn_mfma_f32_16x16x32_bf16(
              af[m], bfr[n], acc[m][n], 0, 0, 0);
    }
    __syncthreads();
  }

#pragma unroll
  for (int n = 0; n < NR; ++n) {
    const int gcol = wc * 32 + n * 16 + fr;
    const float bv = bias[gcol] + t * wtime[gcol];
#pragma unroll
    for (int m = 0; m < MR; ++m) {
      const int grow0 = bm + wr * 32 + m * 16 + (fq << 2);
#pragma unroll
      for (int r = 0; r < 4; ++r) {
        const float kv = acc[m][n][r] + bv;
        const size_t o = (size_t)(grow0 + r) * 64 + gcol;
        if (mode == 0) {
          accb[o] = kv;
          ybf[o] = (bf16_t)(y[o] + cs * kv);
        } else if (mode == 1) {
          accb[o] += ca * kv;
          ybf[o] = (bf16_t)(y[o] + cs * kv);
        } else {
          const float ny = y[o] + cs * (accb[o] + kv);
          y[o] = ny;
          ybf[o] = (bf16_t)ny;
        }
      }
    }
  }
}

// ---------------------------------------------------------------------------
__global__ void prep_weight(const float* __restrict__ W, const float* __restrict__ b,
                            bf16_t* __restrict__ WT, float* __restrict__ bias,
                            float* __restrict__ wtime,
                            int K, int N, int Kpad, int Npad)
{
  int idx = blockIdx.x * 256 + threadIdx.x;
  int total = Npad * Kpad;
  if (idx < total) {
    int n = idx / Kpad, k = idx % Kpad;
    float v = (n < N && k < K) ? W[(size_t)k * N + n] : 0.0f;
    WT[idx] = (bf16_t)v;
  }
  if (idx < Npad) {
    bias[idx]  = (idx < N) ? b[idx] : 0.0f;
    wtime[idx] = (idx < N) ? W[(size_t)K * N + idx] : 0.0f;
  }
}

__global__ void init_y(const float* __restrict__ x, float* __restrict__ y,
                       bf16_t* __restrict__ ybf, int M)
{
  int i = blockIdx.x * 256 + threadIdx.x;
  if (i < M * 64) {
    int m = i >> 6, c = i & 63;
    float v = (c < 2) ? x[m * 2 + c] : 0.0f;
    y[i] = v;
    ybf[i] = (bf16_t)v;
  }
}

__global__ void extract_out(const float* __restrict__ y, float* __restrict__ out, int M)
{
  int i = blockIdx.x * 256 + threadIdx.x;
  if (i < M * 3) {
    int m = i / 3, c = i % 3;
    out[i] = y[(size_t)m * 64 + c];
  }
}

extern "C" void kernel_launch(void* const* d_in, const int* in_sizes, int n_in,
                              void* d_out, int out_size, void* d_ws, size_t ws_size,
                              hipStream_t stream)
{
  (void)in_sizes; (void)n_in; (void)out_size; (void)ws_size;
  const int M = 32768;

  const float* x = (const float*)d_in[0];
  const float* Wp[5]; const float* bp[5];
  for (int i = 0; i < 5; ++i) {
    Wp[i] = (const float*)d_in[1 + 2 * i];
    bp[i] = (const float*)d_in[2 + 2 * i];
  }

  char* ws = (char*)d_ws; size_t off = 0;
  auto alloc = [&](size_t bytes) -> char* {
    char* p = ws + off; off += (bytes + 255) & ~(size_t)255; return p;
  };

  bf16_t* WT[5];
  WT[0] = (bf16_t*)alloc((size_t)1024 * 64 * 2);
  WT[1] = (bf16_t*)alloc((size_t)1024 * 1024 * 2);
  WT[2] = (bf16_t*)alloc((size_t)1024 * 1024 * 2);
  WT[3] = (bf16_t*)alloc((size_t)1024 * 1024 * 2);
  WT[4] = (bf16_t*)alloc((size_t)64 * 1024 * 2);
  float* bias[5]; float* wtm[5];
  for (int i = 0; i < 5; ++i) {
    int Np = (i == 4) ? 64 : 1024;
    bias[i] = (float*)alloc((size_t)Np * 4);
    wtm[i]  = (float*)alloc((size_t)Np * 4);
  }
  float*  y    = (float*)alloc((size_t)M * 64 * 4);
  float*  accb = (float*)alloc((size_t)M * 64 * 4);
  bf16_t* ybf  = (bf16_t*)alloc((size_t)M * 64 * 2);
  bf16_t* act0 = (bf16_t*)alloc((size_t)M * 1024 * 2);
  bf16_t* act1 = (bf16_t*)alloc((size_t)M * 1024 * 2);

  const int Kd[5]  = {50, 1024, 1024, 1024, 1024};
  const int Nd[5]  = {1024, 1024, 1024, 1024, 50};
  const int Kpd[5] = {64, 1024, 1024, 1024, 1024};
  const int Npd[5] = {1024, 1024, 1024, 1024, 64};
  for (int i = 0; i < 5; ++i) {
    int tot = Npd[i] * Kpd[i];
    prep_weight<<<dim3((tot + 255) / 256), 256, 0, stream>>>(
        Wp[i], bp[i], WT[i], bias[i], wtm[i], Kd[i], Nd[i], Kpd[i], Npd[i]);
  }

  init_y<<<dim3((M * 64 + 255) / 256), 256, 0, stream>>>(x, y, ybf, M);

  const float dtv = 1.0f / 32.0f;
  dim3 gL0(M / 128, 1024 / 128);        // 2048 blocks
  dim3 g256(M / 256 * (1024 / 256));    // 512 blocks, %8 == 0
  dim3 gL4(M / 64);                     // 512 blocks = 2/CU

  auto run_net = [&](float t, float ca, float cs, int mode) {
    gemm_bt<128,128,64,2,2,true,true><<<gL0, 256, 0, stream>>>(
        ybf, 64, WT[0], bias[0], wtm[0], t, act0, 1024, M, 64);
    gemm256<1024><<<g256, 256, 0, stream>>>(
        act0, WT[1], bias[1], wtm[1], t, act1, 1024, M, 1024);
    gemm256<1024><<<g256, 256, 0, stream>>>(
        act1, WT[2], bias[2], wtm[2], t, act0, 1024, M, 1024);
    gemm256<1024><<<g256, 256, 0, stream>>>(
        act0, WT[3], bias[3], wtm[3], t, act1, 1024, M, 1024);
    gemm_l4_rk4<<<gL4, 256, 0, stream>>>(
        act1, 1024, WT[4], bias[4], wtm[4], t,
        y, accb, ybf, ca, cs, mode, M, 1024);
  };

  for (int i = 0; i < 32; ++i) {
    const float t0 = i * dtv;
    const float tm = t0 + 0.5f * dtv;
    const float t1 = t0 + dtv;
    run_net(t0, 0.0f, 0.5f * dtv, 0);   // k1
    run_net(tm, 2.0f, 0.5f * dtv, 1);   // k2
    run_net(tm, 2.0f, dtv,        1);   // k3
    run_net(t1, 0.0f, dtv / 6.0f, 2);   // k4
  }

  extract_out<<<dim3((M * 3 + 255) / 256), 256, 0, stream>>>(y, (float*)d_out, M);
}

// Round 10
// 38031.055 us; speedup vs baseline: 1.0124x; 1.0124x over previous
//
#include <hip/hip_runtime.h>
#include <hip/hip_bf16.h>
#include <stdint.h>

// Neural ODE (RK4, 32 steps) over a 5-layer MLP, B=32768, VAR_DIM=50 (pad 64).
// bf16 MFMA GEMMs (16x16x32), fp32 accum, fp32 state y.
// concat(h,t) @ W == h @ W[:K] + (b + t*W[K]) -> time column folded into bias.
// r9: r7 8-wave shape + 2-tile-deep staging (stage T+2 after the mid-tile
//     barrier; vmcnt(0) then drains tile-old loads -> no staging stall) +
//     lgkmcnt(0) before the mid-tile barrier (closes r7's write-after-read
//     window on the fragment reads).

typedef __bf16 bf16_t;
typedef bf16_t bf16x8 __attribute__((ext_vector_type(8)));
typedef float  f32x4  __attribute__((ext_vector_type(4)));

#define DEVI static __device__ __forceinline__

DEVI void gload_lds16(const bf16_t* gsrc, bf16_t* ldst) {
  __builtin_amdgcn_global_load_lds(
      (const __attribute__((address_space(1))) uint32_t*)gsrc,
      (__attribute__((address_space(3))) uint32_t*)ldst,
      16, 0, 0);
}

// ---------------------------------------------------------------------------
// 256x256 tile, BK=64, 8 waves (2Mx4N, 128x64 each), double-buffered LDS.
// LDS swizzle: physical_col_byte = logical ^ bit5*(row&4) ^ bit6*(row&8),
// staged via linear global_load_lds dest + pre-swizzled global SOURCE col.
// Per K-tile T (buf = T&1):
//   read kk1 B frags ; MFMA q00 ; read kk1 A frags ; MFMA q01 ; MFMA q10
//   lgkmcnt(0) ; vmcnt(0) [drains stage(T+1), issued one tile ago] ; barrier
//   stage(T+2) -> buf(T) ; read T+1 kk0 frags from buf^1 ; MFMA q11
// ---------------------------------------------------------------------------
template<int K>
__global__ __launch_bounds__(512, 2) void gemm256(
    const bf16_t* __restrict__ A,     // M x K row-major
    const bf16_t* __restrict__ BT,    // N x K row-major (pre-transposed W)
    const float* __restrict__ bias,
    const float* __restrict__ wtime,
    float t,
    bf16_t* __restrict__ C, int ldc,
    int M, int N)
{
  constexpr int NT = K / 64;          // K-tiles
  static_assert(NT >= 3, "pipeline needs >=3 K-tiles");

  __shared__ __align__(16) bf16_t As[2][256][64];
  __shared__ __align__(16) bf16_t Bs[2][256][64];

  const int tid  = threadIdx.x;
  const int wave = tid >> 6;
  const int lane = tid & 63;
  const int wr = wave >> 2;           // 0..1 -> 128-row half
  const int wc = wave & 3;            // 0..3 -> 64-col strip

  // T1: XCD-aware bijective swizzle (gridDim.x % 8 == 0 by construction)
  int wg = blockIdx.x;
  {
    const int cpx = gridDim.x >> 3;
    wg = (wg & 7) * cpx + (wg >> 3);
  }
  const int nbn = N >> 8;
  const int bm = (wg / nbn) << 8;
  const int bn = (wg % nbn) << 8;

  // staging: dest row r = [buf*256 + h*128 +] wave*8 + (lane>>3)
  //   -> r&4 = lane&32-bit, r&8 = wave&1.  Pre-swizzled SOURCE col.
  const int srow = lane >> 3;
  const int scol = ((lane & 7) << 3) ^ ((lane & 32) >> 1) ^ ((wave & 1) << 5);
  const bf16_t* aS = A  + (size_t)(bm + wave * 8 + srow) * K + scol;
  const bf16_t* bS = BT + (size_t)(bn + wave * 8 + srow) * K + scol;
  bf16_t* aD = &As[0][0][0] + wave * 8 * 64;   // wave-uniform LDS base
  bf16_t* bD = &Bs[0][0][0] + wave * 8 * 64;

  auto stageTile = [&](int kt) {
    const int buf = kt & 1;
#pragma unroll
    for (int h = 0; h < 2; ++h) {
      const bf16_t* srcA = aS + (size_t)(h * 128) * K + kt * 64;
      const bf16_t* srcB = bS + (size_t)(h * 128) * K + kt * 64;
      bf16_t* dstA = aD + (buf * 256 + h * 128) * 64;
      bf16_t* dstB = bD + (buf * 256 + h * 128) * 64;
      gload_lds16(srcA,                  dstA);
      gload_lds16(srcA + (size_t)64 * K, dstA + 64 * 64);
      gload_lds16(srcB,                  dstB);
      gload_lds16(srcB + (size_t)64 * K, dstB + 64 * 64);
    }
  };

  const int fr = lane & 15;
  const int fq = lane >> 4;
  const int rsw = ((fr & 4) << 3) ^ ((fr & 8) << 3);   // byte-XOR from row bits

  bf16x8 ah0[8], ah1[8];   // A frags for mh=0 / mh=1  [m*2+kk]
  bf16x8 bh0[4], bh1[4];   // B frags for nh=0 / nh=1  [n*2+kk]
  f32x4  acc[8][4] = {};

  auto lda_into = [&](bf16x8 (&dst)[8], int buf, int mh) {
    const char* base = (const char*)&As[buf][0][0];
#pragma unroll
    for (int m = 0; m < 4; ++m)
#pragma unroll
      for (int kk = 0; kk < 2; ++kk) {
        int r  = wr * 128 + (mh * 4 + m) * 16 + fr;
        int cb = (kk * 64 + fq * 16) ^ rsw;
        dst[m * 2 + kk] = *(const bf16x8*)(base + r * 128 + cb);
      }
  };
  auto ldb_into = [&](bf16x8 (&dst)[4], int buf, int nh) {
    const char* base = (const char*)&Bs[buf][0][0];
#pragma unroll
    for (int n = 0; n < 2; ++n)
#pragma unroll
      for (int kk = 0; kk < 2; ++kk) {
        int r  = wc * 64 + (nh * 2 + n) * 16 + fr;
        int cb = (kk * 64 + fq * 16) ^ rsw;
        dst[n * 2 + kk] = *(const bf16x8*)(base + r * 128 + cb);
      }
  };
  auto mma_quad = [&](bf16x8 (&a)[8], bf16x8 (&b)[4], int mh, int nh) {
    __builtin_amdgcn_s_setprio(1);
#pragma unroll
    for (int m = 0; m < 4; ++m)
#pragma unroll
      for (int n = 0; n < 2; ++n)
#pragma unroll
        for (int kk = 0; kk < 2; ++kk)
          acc[mh * 4 + m][nh * 2 + n] = __builtin_amdgcn_mfma_f32_16x16x32_bf16(
              a[m * 2 + kk], b[n * 2 + kk],
              acc[mh * 4 + m][nh * 2 + n], 0, 0, 0);
    __builtin_amdgcn_s_setprio(0);
  };

  // prologue: stage tiles 0 and 1; wait for tile0 only (8 of 16 outstanding)
  stageTile(0);
  stageTile(1);
  asm volatile("s_waitcnt vmcnt(8)" ::: "memory");
  __builtin_amdgcn_s_barrier();
  lda_into(ah0, 0, 0);
  ldb_into(bh0, 0, 0);

  for (int t2 = 0; t2 < NT; ++t2) {
    const int buf = t2 & 1;
    ldb_into(bh1, buf, 1);                // 4 reads (this tile, nh=1)
    mma_quad(ah0, bh0, 0, 0);             // q00 (frags read last tile)
    lda_into(ah1, buf, 1);                // 8 reads (this tile, mh=1)
    mma_quad(ah0, bh1, 0, 1);             // q01
    mma_quad(ah1, bh0, 1, 0);             // q10
    asm volatile("s_waitcnt lgkmcnt(0)" ::: "memory");  // own buf(T) reads drained
    asm volatile("s_waitcnt vmcnt(0)" ::: "memory");    // stage(T+1) done (tile-old)
    __builtin_amdgcn_s_barrier();                       // all waves: reads + stages done
    if (t2 + 2 < NT) stageTile(t2 + 2);   // -> buf(T), safe after barrier
    if (t2 + 1 < NT) {
      lda_into(ah0, buf ^ 1, 0);          // T+1 kk-frags overlap q11 MFMAs
      ldb_into(bh0, buf ^ 1, 0);
    }
    mma_quad(ah1, bh1, 1, 1);             // q11 (operands already in regs)
  }

  // epilogue: bias(t) + ReLU, bf16 out
#pragma unroll
  for (int n = 0; n < 4; ++n) {
    const int gcol = bn + wc * 64 + n * 16 + fr;
    const float bv = bias[gcol] + t * wtime[gcol];
#pragma unroll
    for (int m = 0; m < 8; ++m) {
      const int grow0 = bm + wr * 128 + m * 16 + (fq << 2);
#pragma unroll
      for (int r = 0; r < 4; ++r) {
        float v = acc[m][n][r] + bv;
        v = v > 0.0f ? v : 0.0f;
        C[(size_t)(grow0 + r) * ldc + gcol] = (bf16_t)v;
      }
    }
  }
}

// ---------------------------------------------------------------------------
// 128^2 kernel for layer 0 (K=64), full bank-spread swizzle.
// ---------------------------------------------------------------------------
template<int BM, int BN, int BK, int WROWS, int WCOLS, bool RELU, bool OUT_BF16>
__global__ __launch_bounds__(256) void gemm_bt(
    const bf16_t* __restrict__ A, int lda,
    const bf16_t* __restrict__ BT,
    const float* __restrict__ bias,
    const float* __restrict__ wtime,
    float t,
    void* __restrict__ Cv, int ldc,
    int M, int K)
{
  static_assert(BK == 64, "swizzle assumes BK=64");
  constexpr int MR  = BM / WROWS / 16;
  constexpr int NR  = BN / WCOLS / 16;
  constexpr int TPR = BK / 8;        // 8
  constexpr int RPW = 64 / TPR;      // 8
  constexpr int RPL = 4 * RPW;       // 32
  static_assert(BM % RPL == 0 && BN % RPL == 0, "tile staging mismatch");

  __shared__ bf16_t As[BM][BK];
  __shared__ bf16_t Bs[BN][BK];

  const int tid  = threadIdx.x;
  const int wave = tid >> 6;
  const int lane = tid & 63;
  const int wr = wave / WCOLS;
  const int wc = wave % WCOLS;
  const int bm = blockIdx.x * BM;
  const int bn = blockIdx.y * BN;
  const int lrow = lane >> 3;
  const int lcol = (((lane & 7) << 3) ^ ((lane & 32) >> 1) ^ ((wave & 1) << 5));

  const int fr = lane & 15;
  const int fq = lane >> 4;
  const int esw = ((fr & 4) << 2) ^ ((fr & 8) << 2);  // element-XOR from row bits

  f32x4 acc[MR][NR] = {};

  for (int k0 = 0; k0 < K; k0 += BK) {
#pragma unroll
    for (int i = 0; i < BM / RPL; ++i) {
      const int rb = i * RPL + wave * RPW;
      gload_lds16(&A[(size_t)(bm + rb + lrow) * lda + k0 + lcol], &As[rb][0]);
    }
#pragma unroll
    for (int i = 0; i < BN / RPL; ++i) {
      const int rb = i * RPL + wave * RPW;
      gload_lds16(&BT[(size_t)(bn + rb + lrow) * K + k0 + lcol], &Bs[rb][0]);
    }
    __syncthreads();
#pragma unroll
    for (int kk = 0; kk < BK / 32; ++kk) {
      bf16x8 af[MR], bfr[NR];
      const int ecol = (kk * 32 + fq * 8) ^ esw;
#pragma unroll
      for (int m = 0; m < MR; ++m)
        af[m] = *(const bf16x8*)&As[wr * (BM / WROWS) + m * 16 + fr][ecol];
#pragma unroll
      for (int n = 0; n < NR; ++n)
        bfr[n] = *(const bf16x8*)&Bs[wc * (BN / WCOLS) + n * 16 + fr][ecol];
#pragma unroll
      for (int m = 0; m < MR; ++m)
#pragma unroll
        for (int n = 0; n < NR; ++n)
          acc[m][n] = __builtin_amdgcn_mfma_f32_16x16x32_bf16(
              af[m], bfr[n], acc[m][n], 0, 0, 0);
    }
    __syncthreads();
  }

#pragma unroll
  for (int n = 0; n < NR; ++n) {
    const int gcol = bn + wc * (BN / WCOLS) + n * 16 + fr;
    const float bv = bias[gcol] + t * wtime[gcol];
#pragma unroll
    for (int m = 0; m < MR; ++m) {
      const int grow0 = bm + wr * (BM / WROWS) + m * 16 + (fq << 2);
#pragma unroll
      for (int r = 0; r < 4; ++r) {
        float v = acc[m][n][r] + bv;
        if (RELU) v = v > 0.0f ? v : 0.0f;
        if constexpr (OUT_BF16)
          ((bf16_t*)Cv)[(size_t)(grow0 + r) * ldc + gcol] = (bf16_t)v;
        else
          ((float*)Cv)[(size_t)(grow0 + r) * ldc + gcol] = v;
      }
    }
  }
}

// ---------------------------------------------------------------------------
// Layer 4 (N=64, K=1024) with RK4 combine fused into the epilogue.
// BM=64, BN=64, 4 waves (2x2) -> 512 blocks = 2 blocks/CU.  Swizzled LDS.
// ---------------------------------------------------------------------------
__global__ __launch_bounds__(256) void gemm_l4_rk4(
    const bf16_t* __restrict__ A, int lda,
    const bf16_t* __restrict__ BT,
    const float* __restrict__ bias,
    const float* __restrict__ wtime,
    float t,
    float* __restrict__ y, float* __restrict__ accb,
    bf16_t* __restrict__ ybf,
    float ca, float cs, int mode,
    int M, int K)
{
  constexpr int BM = 64, BN = 64, BK = 64;
  constexpr int MR = 2, NR = 2;

  __shared__ bf16_t As[BM][BK];
  __shared__ bf16_t Bs[BN][BK];

  const int tid  = threadIdx.x;
  const int wave = tid >> 6;
  const int lane = tid & 63;
  const int wr = wave >> 1;
  const int wc = wave & 1;
  const int bm = blockIdx.x * BM;
  const int lrow = lane >> 3;
  const int lcol = (((lane & 7) << 3) ^ ((lane & 32) >> 1) ^ ((wave & 1) << 5));

  const int fr = lane & 15;
  const int fq = lane >> 4;
  const int esw = ((fr & 4) << 2) ^ ((fr & 8) << 2);

  f32x4 acc[MR][NR] = {};

  for (int k0 = 0; k0 < K; k0 += BK) {
#pragma unroll
    for (int i = 0; i < 2; ++i) {
      const int rb = i * 32 + wave * 8;
      gload_lds16(&A[(size_t)(bm + rb + lrow) * lda + k0 + lcol], &As[rb][0]);
    }
#pragma unroll
    for (int i = 0; i < 2; ++i) {
      const int rb = i * 32 + wave * 8;
      gload_lds16(&BT[(size_t)(rb + lrow) * K + k0 + lcol], &Bs[rb][0]);
    }
    __syncthreads();
#pragma unroll
    for (int kk = 0; kk < 2; ++kk) {
      bf16x8 af[MR], bfr[NR];
      const int ecol = (kk * 32 + fq * 8) ^ esw;
#pragma unroll
      for (int m = 0; m < MR; ++m)
        af[m] = *(const bf16x8*)&As[wr * 32 + m * 16 + fr][ecol];
#pragma unroll
      for (int n = 0; n < NR; ++n)
        bfr[n] = *(const bf16x8*)&Bs[wc * 32 + n * 16 + fr][ecol];
#pragma unroll
      for (int m = 0; m < MR; ++m)
#pragma unroll
        for (int n = 0; n < NR; ++n)
          acc[m][n] = __builtin_amdgcn_mfma_f32_16x16x32_bf16(
              af[m], bfr[n], acc[m][n], 0, 0, 0);
    }
    __syncthreads();
  }

#pragma unroll
  for (int n = 0; n < NR; ++n) {
    const int gcol = wc * 32 + n * 16 + fr;
    const float bv = bias[gcol] + t * wtime[gcol];
#pragma unroll
    for (int m = 0; m < MR; ++m) {
      const int grow0 = bm + wr * 32 + m * 16 + (fq << 2);
#pragma unroll
      for (int r = 0; r < 4; ++r) {
        const float kv = acc[m][n][r] + bv;
        const size_t o = (size_t)(grow0 + r) * 64 + gcol;
        if (mode == 0) {
          accb[o] = kv;
          ybf[o] = (bf16_t)(y[o] + cs * kv);
        } else if (mode == 1) {
          accb[o] += ca * kv;
          ybf[o] = (bf16_t)(y[o] + cs * kv);
        } else {
          const float ny = y[o] + cs * (accb[o] + kv);
          y[o] = ny;
          ybf[o] = (bf16_t)ny;
        }
      }
    }
  }
}

// ---------------------------------------------------------------------------
__global__ void prep_weight(const float* __restrict__ W, const float* __restrict__ b,
                            bf16_t* __restrict__ WT, float* __restrict__ bias,
                            float* __restrict__ wtime,
                            int K, int N, int Kpad, int Npad)
{
  int idx = blockIdx.x * 256 + threadIdx.x;
  int total = Npad * Kpad;
  if (idx < total) {
    int n = idx / Kpad, k = idx % Kpad;
    float v = (n < N && k < K) ? W[(size_t)k * N + n] : 0.0f;
    WT[idx] = (bf16_t)v;
  }
  if (idx < Npad) {
    bias[idx]  = (idx < N) ? b[idx] : 0.0f;
    wtime[idx] = (idx < N) ? W[(size_t)K * N + idx] : 0.0f;
  }
}

__global__ void init_y(const float* __restrict__ x, float* __restrict__ y,
                       bf16_t* __restrict__ ybf, int M)
{
  int i = blockIdx.x * 256 + threadIdx.x;
  if (i < M * 64) {
    int m = i >> 6, c = i & 63;
    float v = (c < 2) ? x[m * 2 + c] : 0.0f;
    y[i] = v;
    ybf[i] = (bf16_t)v;
  }
}

__global__ void extract_out(const float* __restrict__ y, float* __restrict__ out, int M)
{
  int i = blockIdx.x * 256 + threadIdx.x;
  if (i < M * 3) {
    int m = i / 3, c = i % 3;
    out[i] = y[(size_t)m * 64 + c];
  }
}

extern "C" void kernel_launch(void* const* d_in, const int* in_sizes, int n_in,
                              void* d_out, int out_size, void* d_ws, size_t ws_size,
                              hipStream_t stream)
{
  (void)in_sizes; (void)n_in; (void)out_size; (void)ws_size;
  const int M = 32768;

  const float* x = (const float*)d_in[0];
  const float* Wp[5]; const float* bp[5];
  for (int i = 0; i < 5; ++i) {
    Wp[i] = (const float*)d_in[1 + 2 * i];
    bp[i] = (const float*)d_in[2 + 2 * i];
  }

  char* ws = (char*)d_ws; size_t off = 0;
  auto alloc = [&](size_t bytes) -> char* {
    char* p = ws + off; off += (bytes + 255) & ~(size_t)255; return p;
  };

  bf16_t* WT[5];
  WT[0] = (bf16_t*)alloc((size_t)1024 * 64 * 2);
  WT[1] = (bf16_t*)alloc((size_t)1024 * 1024 * 2);
  WT[2] = (bf16_t*)alloc((size_t)1024 * 1024 * 2);
  WT[3] = (bf16_t*)alloc((size_t)1024 * 1024 * 2);
  WT[4] = (bf16_t*)alloc((size_t)64 * 1024 * 2);
  float* bias[5]; float* wtm[5];
  for (int i = 0; i < 5; ++i) {
    int Np = (i == 4) ? 64 : 1024;
    bias[i] = (float*)alloc((size_t)Np * 4);
    wtm[i]  = (float*)alloc((size_t)Np * 4);
  }
  float*  y    = (float*)alloc((size_t)M * 64 * 4);
  float*  accb = (float*)alloc((size_t)M * 64 * 4);
  bf16_t* ybf  = (bf16_t*)alloc((size_t)M * 64 * 2);
  bf16_t* act0 = (bf16_t*)alloc((size_t)M * 1024 * 2);
  bf16_t* act1 = (bf16_t*)alloc((size_t)M * 1024 * 2);

  const int Kd[5]  = {50, 1024, 1024, 1024, 1024};
  const int Nd[5]  = {1024, 1024, 1024, 1024, 50};
  const int Kpd[5] = {64, 1024, 1024, 1024, 1024};
  const int Npd[5] = {1024, 1024, 1024, 1024, 64};
  for (int i = 0; i < 5; ++i) {
    int tot = Npd[i] * Kpd[i];
    prep_weight<<<dim3((tot + 255) / 256), 256, 0, stream>>>(
        Wp[i], bp[i], WT[i], bias[i], wtm[i], Kd[i], Nd[i], Kpd[i], Npd[i]);
  }

  init_y<<<dim3((M * 64 + 255) / 256), 256, 0, stream>>>(x, y, ybf, M);

  const float dtv = 1.0f / 32.0f;
  dim3 gL0(M / 128, 1024 / 128);        // 2048 blocks
  dim3 g256(M / 256 * (1024 / 256));    // 512 blocks, %8 == 0
  dim3 gL4(M / 64);                     // 512 blocks = 2/CU

  auto run_net = [&](float t, float ca, float cs, int mode) {
    gemm_bt<128,128,64,2,2,true,true><<<gL0, 256, 0, stream>>>(
        ybf, 64, WT[0], bias[0], wtm[0], t, act0, 1024, M, 64);
    gemm256<1024><<<g256, 512, 0, stream>>>(
        act0, WT[1], bias[1], wtm[1], t, act1, 1024, M, 1024);
    gemm256<1024><<<g256, 512, 0, stream>>>(
        act1, WT[2], bias[2], wtm[2], t, act0, 1024, M, 1024);
    gemm256<1024><<<g256, 512, 0, stream>>>(
        act0, WT[3], bias[3], wtm[3], t, act1, 1024, M, 1024);
    gemm_l4_rk4<<<gL4, 256, 0, stream>>>(
        act1, 1024, WT[4], bias[4], wtm[4], t,
        y, accb, ybf, ca, cs, mode, M, 1024);
  };

  for (int i = 0; i < 32; ++i) {
    const float t0 = i * dtv;
    const float tm = t0 + 0.5f * dtv;
    const float t1 = t0 + dtv;
    run_net(t0, 0.0f, 0.5f * dtv, 0);   // k1
    run_net(tm, 2.0f, 0.5f * dtv, 1);   // k2
    run_net(tm, 2.0f, dtv,        1);   // k3
    run_net(t1, 0.0f, dtv / 6.0f, 2);   // k4
  }

  extract_out<<<dim3((M * 3 + 255) / 256), 256, 0, stream>>>(y, (float*)d_out, M);
}